// Round 2
// baseline (4486.832 us; speedup 1.0000x reference)
//
#include <hip/hip_runtime.h>
#include <math.h>

// Problem constants (ResidualVQ: B=8, N=4096, D=512, C=1024, Q=8)
#define B_   8
#define N_   4096
#define D_   512
#define C_   1024
#define Q_   8
#define ROWS (B_ * N_)   // 32768 token rows

// GEMM tiling
#define BM   64          // rows per workgroup
#define BNC  64          // codes per chunk
#define BK   32          // K tile
#define LSTR 68          // LDS row stride (BM + 4 pad, keeps float4 alignment)

// -------------------------------------------------------------------------
// Precompute ||e||^2 for every code of every stage: norms[Q_*C_]
// One wave per code; grid = Q_*C_/4 blocks of 256 threads.
__global__ __launch_bounds__(256)
void code_norms_kernel(const float* __restrict__ cb, float* __restrict__ norms) {
    const int code = blockIdx.x * 4 + (threadIdx.x >> 6);   // [0, Q_*C_)
    const int lane = threadIdx.x & 63;
    const float* p = cb + (size_t)code * D_;
    float s = 0.f;
    #pragma unroll
    for (int d = lane * 4; d < D_; d += 64 * 4) {           // 2 float4 per lane
        float4 v = *(const float4*)(p + d);
        s += v.x * v.x + v.y * v.y + v.z * v.z + v.w * v.w;
    }
    #pragma unroll
    for (int m = 1; m < 64; m <<= 1) s += __shfl_xor(s, m);
    if (lane == 0) norms[code] = s;
}

// -------------------------------------------------------------------------
// One RVQ stage, fully fused:
//   scores = -2 * (res @ cb^T) + ||cb||^2   (tiled f32 GEMM, never materialized)
//   idx    = argmin over codes (first-min tie-break, matches jnp.argmin)
//   newres = res - cb[idx];  loss += mean(newres^2)
//   dst    = newres            (stages 0..Q-2)
//   dst    = x - newres = qout (last stage)
// NOTE: indices are written as FLOAT values — the harness reads the whole
// concatenated d_out as float32 (mixed-dtype tuple), so int bit patterns
// read back as denormals (~0). Proven by round-1 failure signature.
__global__ __launch_bounds__(256)
void rvq_stage_kernel(const float* __restrict__ src,    // residual in  [ROWS][D_]
                      float* __restrict__ dst,          // residual out (qout region)
                      const float* __restrict__ x,      // original input
                      const float* __restrict__ cb,     // stage codebook [C_][D_]
                      const float* __restrict__ norms,  // [C_]
                      float* __restrict__ idx_out,      // [ROWS][Q_]  (float values!)
                      float* __restrict__ loss_out,     // &losses[q]
                      int q, int is_last)
{
    __shared__ float Asub[BK][LSTR];   // residual tile, transposed [k][m]
    __shared__ float Bsub[BK][LSTR];   // codebook tile, transposed [k][c]
    __shared__ int   idx_sh[BM];

    const int tid = threadIdx.x;
    const int tx  = tid & 15;          // code dim   (16 threads)
    const int ty  = tid >> 4;          // row dim    (16 threads)
    const int rowBase = blockIdx.x * BM;

    // staging coords: 256 threads move a 64x32 f32 tile (transposing)
    const int lr = tid >> 3;           // 0..31  (row within half-tile)
    const int lc = (tid & 7) * 4;      // 0,4,...,28 (k offset, float4)

    float minv[4];
    int   mini[4];
    #pragma unroll
    for (int i = 0; i < 4; ++i) { minv[i] = INFINITY; mini[i] = 0; }

    for (int chunk = 0; chunk < C_ / BNC; ++chunk) {
        float acc[4][4];
        #pragma unroll
        for (int i = 0; i < 4; ++i)
            #pragma unroll
            for (int j = 0; j < 4; ++j) acc[i][j] = 0.f;

        for (int kt = 0; kt < D_ / BK; ++kt) {
            const int kBase = kt * BK;
            __syncthreads();   // previous compute done before overwriting LDS
            // stage A (residual rows), transposed into [k][m]
            #pragma unroll
            for (int r2 = 0; r2 < 2; ++r2) {
                const int row = lr + r2 * 32;
                float4 v = *(const float4*)(src + (size_t)(rowBase + row) * D_ + kBase + lc);
                Asub[lc + 0][row] = v.x;
                Asub[lc + 1][row] = v.y;
                Asub[lc + 2][row] = v.z;
                Asub[lc + 3][row] = v.w;
            }
            // stage B (codebook rows), transposed into [k][c]
            #pragma unroll
            for (int r2 = 0; r2 < 2; ++r2) {
                const int code = lr + r2 * 32;
                float4 v = *(const float4*)(cb + (size_t)(chunk * BNC + code) * D_ + kBase + lc);
                Bsub[lc + 0][code] = v.x;
                Bsub[lc + 1][code] = v.y;
                Bsub[lc + 2][code] = v.z;
                Bsub[lc + 3][code] = v.w;
            }
            __syncthreads();
            #pragma unroll
            for (int kk = 0; kk < BK; ++kk) {
                float a[4], b[4];
                *(float4*)a = *(const float4*)&Asub[kk][ty * 4];
                *(float4*)b = *(const float4*)&Bsub[kk][tx * 4];
                #pragma unroll
                for (int i = 0; i < 4; ++i)
                    #pragma unroll
                    for (int j = 0; j < 4; ++j)
                        acc[i][j] = fmaf(a[i], b[j], acc[i][j]);
            }
        }
        // fold this chunk into the running argmin (ascending code index)
        const int cbase = chunk * BNC + tx * 4;
        float nr[4];
        *(float4*)nr = *(const float4*)(norms + cbase);
        #pragma unroll
        for (int i = 0; i < 4; ++i)
            #pragma unroll
            for (int j = 0; j < 4; ++j) {
                const float s = fmaf(-2.f, acc[i][j], nr[j]);
                if (s < minv[i]) { minv[i] = s; mini[i] = cbase + j; }
            }
    }

    // reduce argmin across the 16 code-lanes (lane bits 0..3 within the wave)
    #pragma unroll
    for (int i = 0; i < 4; ++i) {
        float v = minv[i];
        int   ix = mini[i];
        #pragma unroll
        for (int m = 1; m < 16; m <<= 1) {
            const float ov  = __shfl_xor(v, m);
            const int   oix = __shfl_xor(ix, m);
            if (ov < v || (ov == v && oix < ix)) { v = ov; ix = oix; }
        }
        minv[i] = v; mini[i] = ix;
    }
    if (tx == 0) {
        #pragma unroll
        for (int i = 0; i < 4; ++i) {
            const int row = ty * 4 + i;
            idx_sh[row] = mini[i];
            idx_out[(size_t)(rowBase + row) * Q_ + q] = (float)mini[i];
        }
    }
    __syncthreads();

    // update phase: newres = res - cb[idx]; loss partial; write dst
    float lsum = 0.f;
    #pragma unroll 4
    for (int e4 = tid; e4 < BM * D_ / 4; e4 += 256) {
        const int row  = e4 >> 7;          // / (D_/4)
        const int d    = (e4 & 127) * 4;
        const int code = idx_sh[row];
        const size_t off = (size_t)(rowBase + row) * D_ + d;
        float4 r = *(const float4*)(src + off);
        float4 e = *(const float4*)(cb + (size_t)code * D_ + d);
        float4 nrv = make_float4(r.x - e.x, r.y - e.y, r.z - e.z, r.w - e.w);
        lsum += nrv.x * nrv.x + nrv.y * nrv.y + nrv.z * nrv.z + nrv.w * nrv.w;
        if (is_last) {
            float4 xv = *(const float4*)(x + off);
            *(float4*)(dst + off) = make_float4(xv.x - nrv.x, xv.y - nrv.y,
                                                xv.z - nrv.z, xv.w - nrv.w);
        } else {
            *(float4*)(dst + off) = nrv;
        }
    }
    #pragma unroll
    for (int m = 1; m < 64; m <<= 1) lsum += __shfl_xor(lsum, m);
    if ((tid & 63) == 0)
        atomicAdd(loss_out, lsum * (1.0f / ((float)ROWS * (float)D_)));
}

// -------------------------------------------------------------------------
extern "C" void kernel_launch(void* const* d_in, const int* in_sizes, int n_in,
                              void* d_out, int out_size, void* d_ws, size_t ws_size,
                              hipStream_t stream) {
    const float* x  = (const float*)d_in[0];   // [B,N,D]
    const float* cb = (const float*)d_in[1];   // [Q,C,D]

    float* qout    = (float*)d_out;                                  // [ROWS*D_]
    float* idx_out = (float*)d_out + (size_t)ROWS * D_;              // [ROWS*Q_] as floats
    float* losses  = (float*)d_out + (size_t)ROWS * D_ + (size_t)ROWS * Q_;  // [Q_]

    float* norms = (float*)d_ws;               // Q_*C_ floats (32 KB)

    hipMemsetAsync(losses, 0, Q_ * sizeof(float), stream);
    code_norms_kernel<<<Q_ * C_ / 4, 256, 0, stream>>>(cb, norms);

    for (int q = 0; q < Q_; ++q) {
        const float* src = (q == 0) ? x : qout;   // residual lives in qout region
        rvq_stage_kernel<<<ROWS / BM, 256, 0, stream>>>(
            src, qout, x,
            cb + (size_t)q * C_ * D_,
            norms + (size_t)q * C_,
            idx_out, losses + q,
            q, (q == Q_ - 1) ? 1 : 0);
    }
}

// Round 3
// 3253.862 us; speedup vs baseline: 1.3789x; 1.3789x over previous
//
#include <hip/hip_runtime.h>
#include <math.h>

// Problem constants (ResidualVQ: B=8, N=4096, D=512, C=1024, Q=8)
#define B_   8
#define N_   4096
#define D_   512
#define C_   1024
#define Q_   8
#define ROWS (B_ * N_)   // 32768 token rows

#define TAU  0.25f       // rescue margin; approx-score error bound ~3e-4

typedef __attribute__((ext_vector_type(8))) short bf16x8;
typedef __attribute__((ext_vector_type(4))) float f32x4;

// round-to-nearest-even f32 -> bf16 (bits)
__device__ __forceinline__ unsigned short bf16rn(float f) {
    unsigned int u = __builtin_bit_cast(unsigned int, f);
    return (unsigned short)((u + 0x7fffu + ((u >> 16) & 1u)) >> 16);
}
__device__ __forceinline__ float bf16f(unsigned short h) {
    unsigned int u = ((unsigned int)h) << 16;
    return __builtin_bit_cast(float, u);
}
// LDS byte offset for tile [row][32 bf16], XOR-swizzled (<=2-way conflicts)
__device__ __forceinline__ int swzoff(int row, int q) {
    return row * 64 + ((q ^ ((row >> 1) & 3)) << 4);
}

// -------------------------------------------------------------------------
// codebook f32 -> hi/lo bf16 (once per call)
__global__ __launch_bounds__(256)
void cb_convert_kernel(const float* __restrict__ cb,
                       unsigned short* __restrict__ hi,
                       unsigned short* __restrict__ lo) {
    const int i4 = blockIdx.x * 256 + threadIdx.x;      // float4 index
    float4 v = ((const float4*)cb)[i4];
    ushort4 h, l;
    h.x = bf16rn(v.x); l.x = bf16rn(v.x - bf16f(h.x));
    h.y = bf16rn(v.y); l.y = bf16rn(v.y - bf16f(h.y));
    h.z = bf16rn(v.z); l.z = bf16rn(v.z - bf16f(h.z));
    h.w = bf16rn(v.w); l.w = bf16rn(v.w - bf16f(h.w));
    ((ushort4*)hi)[i4] = h;
    ((ushort4*)lo)[i4] = l;
}

// ||e||^2 for every code of every stage (exact f32)
__global__ __launch_bounds__(256)
void code_norms_kernel(const float* __restrict__ cb, float* __restrict__ norms) {
    const int code = blockIdx.x * 4 + (threadIdx.x >> 6);
    const int lane = threadIdx.x & 63;
    const float* p = cb + (size_t)code * D_;
    float s = 0.f;
    #pragma unroll
    for (int d = lane * 4; d < D_; d += 256) {
        float4 v = *(const float4*)(p + d);
        s += v.x * v.x + v.y * v.y + v.z * v.z + v.w * v.w;
    }
    #pragma unroll
    for (int m = 1; m < 64; m <<= 1) s += __shfl_xor(s, m);
    if (lane == 0) norms[code] = s;
}

// -------------------------------------------------------------------------
// Split-bf16 MFMA scoring GEMM with per-row top-2 tracking.
// grid = (ROWS/128, 2 halves of C). Block: 256 thr = 4 waves (2 row x 2 code).
// Each block: 128 rows x 512 codes (4 chunks of 128). Wave tile 64x64.
__global__ __launch_bounds__(256, 2)
void rvq_gemm_kernel(const float* __restrict__ src,          // residual [ROWS][D_]
                     const unsigned short* __restrict__ cbh, // stage cb hi [C_][D_]
                     const unsigned short* __restrict__ cbl, // stage cb lo
                     const float* __restrict__ norms_s,      // [C_]
                     float* __restrict__ st_m1,              // [4][ROWS]
                     float* __restrict__ st_m2,              // [4][ROWS]
                     int* __restrict__ st_i1)                // [4][ROWS]
{
    __shared__ char lds[32768];
    char* AhiB = lds;
    char* AloB = lds + 8192;
    char* BhiB = lds + 16384;
    char* BloB = lds + 24576;

    const int tid  = threadIdx.x;
    const int lane = tid & 63;
    const int lc   = lane & 15;        // code lane / row lane within frag
    const int lq   = lane >> 4;        // k-chunk of fragment
    const int wv   = tid >> 6;
    const int wr   = wv >> 1;          // wave row-half (0..1)
    const int wc   = wv & 1;           // wave code-half (0..1)
    const int rowBase = blockIdx.x * 128;
    const int half = blockIdx.y;

    // carried top-2 per owner lane (each lane owns row (lc>>2)*16 + lq*4 + (lc&3))
    float c_m1 = INFINITY, c_m2 = INFINITY;
    int   c_i1 = 0;

    // staging coords
    const int arow  = tid >> 1;        // 0..127
    const int ahalf = tid & 1;         // which 16-k half

    for (int chunk = 0; chunk < 4; ++chunk) {
        const int codeBase = half * 512 + chunk * 128;
        f32x4 acc[4][4];
        #pragma unroll
        for (int m = 0; m < 4; ++m)
            #pragma unroll
            for (int n = 0; n < 4; ++n) acc[m][n] = (f32x4){0.f, 0.f, 0.f, 0.f};

        for (int kt = 0; kt < D_ / 32; ++kt) {
            __syncthreads();   // previous compute finished before restaging
            // ---- stage A (residual f32 -> hi/lo bf16 in regs -> LDS)
            {
                const float* ap = src + (size_t)(rowBase + arow) * D_ + kt * 32 + ahalf * 16;
                float fv[16];
                *(float4*)&fv[0]  = ((const float4*)ap)[0];
                *(float4*)&fv[4]  = ((const float4*)ap)[1];
                *(float4*)&fv[8]  = ((const float4*)ap)[2];
                *(float4*)&fv[12] = ((const float4*)ap)[3];
                bf16x8 H0, H1, L0, L1;
                #pragma unroll
                for (int j = 0; j < 8; ++j) {
                    unsigned short h0 = bf16rn(fv[j]);
                    H0[j] = (short)h0;
                    L0[j] = (short)bf16rn(fv[j] - bf16f(h0));
                    unsigned short h1 = bf16rn(fv[j + 8]);
                    H1[j] = (short)h1;
                    L1[j] = (short)bf16rn(fv[j + 8] - bf16f(h1));
                }
                const int q0 = ahalf * 2;
                *(bf16x8*)(AhiB + swzoff(arow, q0))     = H0;
                *(bf16x8*)(AhiB + swzoff(arow, q0 + 1)) = H1;
                *(bf16x8*)(AloB + swzoff(arow, q0))     = L0;
                *(bf16x8*)(AloB + swzoff(arow, q0 + 1)) = L1;
            }
            // ---- stage B (pre-converted bf16 hi/lo)
            {
                const size_t boff = (size_t)(codeBase + arow) * D_ + kt * 32 + ahalf * 16;
                bf16x8 bh0 = *(const bf16x8*)(cbh + boff);
                bf16x8 bh1 = *(const bf16x8*)(cbh + boff + 8);
                bf16x8 bl0 = *(const bf16x8*)(cbl + boff);
                bf16x8 bl1 = *(const bf16x8*)(cbl + boff + 8);
                const int q0 = ahalf * 2;
                *(bf16x8*)(BhiB + swzoff(arow, q0))     = bh0;
                *(bf16x8*)(BhiB + swzoff(arow, q0 + 1)) = bh1;
                *(bf16x8*)(BloB + swzoff(arow, q0))     = bl0;
                *(bf16x8*)(BloB + swzoff(arow, q0 + 1)) = bl1;
            }
            __syncthreads();
            // ---- fragments + MFMA (3 split terms, shared accumulator)
            bf16x8 ah[4], al[4], bh[4], bl[4];
            #pragma unroll
            for (int m = 0; m < 4; ++m) {
                const int r = wr * 64 + m * 16 + lc;
                ah[m] = *(const bf16x8*)(AhiB + swzoff(r, lq));
                al[m] = *(const bf16x8*)(AloB + swzoff(r, lq));
            }
            #pragma unroll
            for (int n = 0; n < 4; ++n) {
                const int c = wc * 64 + n * 16 + lc;
                bh[n] = *(const bf16x8*)(BhiB + swzoff(c, lq));
                bl[n] = *(const bf16x8*)(BloB + swzoff(c, lq));
            }
            #pragma unroll
            for (int m = 0; m < 4; ++m)
                #pragma unroll
                for (int n = 0; n < 4; ++n) {
                    acc[m][n] = __builtin_amdgcn_mfma_f32_16x16x32_bf16(ah[m], bh[n], acc[m][n], 0, 0, 0);
                    acc[m][n] = __builtin_amdgcn_mfma_f32_16x16x32_bf16(ah[m], bl[n], acc[m][n], 0, 0, 0);
                    acc[m][n] = __builtin_amdgcn_mfma_f32_16x16x32_bf16(al[m], bh[n], acc[m][n], 0, 0, 0);
                }
        }

        // ---- fold chunk scores into carried top-2
        const int cbase = codeBase + wc * 64;
        const float nrm0 = norms_s[cbase + lc];
        const float nrm1 = norms_s[cbase + 16 + lc];
        const float nrm2 = norms_s[cbase + 32 + lc];
        const float nrm3 = norms_s[cbase + 48 + lc];
        #pragma unroll
        for (int m = 0; m < 4; ++m) {
            #pragma unroll
            for (int r = 0; r < 4; ++r) {
                float s0 = fmaf(-2.f, acc[m][0][r], nrm0);
                float s1 = fmaf(-2.f, acc[m][1][r], nrm1);
                float s2 = fmaf(-2.f, acc[m][2][r], nrm2);
                float s3 = fmaf(-2.f, acc[m][3][r], nrm3);
                float m1 = s0, m2 = INFINITY;
                int   i1 = cbase + lc;
                if (s1 < m1) { m2 = m1; m1 = s1; i1 = cbase + 16 + lc; } else m2 = fminf(m2, s1);
                if (s2 < m1) { m2 = m1; m1 = s2; i1 = cbase + 32 + lc; } else m2 = fminf(m2, s2);
                if (s3 < m1) { m2 = m1; m1 = s3; i1 = cbase + 48 + lc; } else m2 = fminf(m2, s3);
                // butterfly over the 16 code lanes
                #pragma unroll
                for (int d = 1; d < 16; d <<= 1) {
                    float om1 = __shfl_xor(m1, d);
                    int   oi1 = __shfl_xor(i1, d);
                    float om2 = __shfl_xor(m2, d);
                    bool take = (om1 < m1) || (om1 == m1 && oi1 < i1);
                    float lose1 = take ? m1 : om1;
                    m2 = fminf(fminf(m2, om2), lose1);
                    m1 = take ? om1 : m1;
                    i1 = take ? oi1 : i1;
                }
                // owner lane merges
                if (lc == (m * 4 + r)) {
                    bool take = (m1 < c_m1) || (m1 == c_m1 && i1 < c_i1);
                    float lose1 = take ? c_m1 : m1;
                    c_m2 = fminf(fminf(c_m2, m2), lose1);
                    c_m1 = take ? m1 : c_m1;
                    c_i1 = take ? i1 : c_i1;
                }
            }
        }
    }

    // each lane owns one row; write its quarter's state
    const int myrow = rowBase + wr * 64 + (lc >> 2) * 16 + lq * 4 + (lc & 3);
    const int quarter = half * 2 + wc;
    st_m1[quarter * ROWS + myrow] = c_m1;
    st_m2[quarter * ROWS + myrow] = c_m2;
    st_i1[quarter * ROWS + myrow] = c_i1;
}

// -------------------------------------------------------------------------
// merge 4 quarters -> final idx + rescue flag
__global__ __launch_bounds__(256)
void merge_kernel(const float* __restrict__ st_m1, const float* __restrict__ st_m2,
                  const int* __restrict__ st_i1,
                  int* __restrict__ idx_i, int* __restrict__ flags,
                  float* __restrict__ idx_f, int q) {
    const int row = blockIdx.x * 256 + threadIdx.x;
    float m1 = st_m1[row], m2 = st_m2[row];
    int   i1 = st_i1[row];
    #pragma unroll
    for (int qt = 1; qt < 4; ++qt) {
        float om1 = st_m1[qt * ROWS + row];
        float om2 = st_m2[qt * ROWS + row];
        int   oi1 = st_i1[qt * ROWS + row];
        if (om1 < m1) { m2 = fminf(m1, om2); m1 = om1; i1 = oi1; }
        else          { m2 = fminf(m2, om1); }
    }
    idx_i[row] = i1;
    idx_f[(size_t)row * Q_ + q] = (float)i1;
    flags[row] = (m2 - m1 < TAU) ? 1 : 0;
}

// -------------------------------------------------------------------------
// exact-f32 re-argmin for flagged (near-tie) rows. One wave per 256 codes.
__global__ __launch_bounds__(256)
void rescue_kernel(const float* __restrict__ src, const float* __restrict__ cb,
                   const float* __restrict__ norms_s,
                   int* __restrict__ idx_i, float* __restrict__ idx_f,
                   const int* __restrict__ flags, int q) {
    __shared__ int flg[64];
    __shared__ float redM[4];
    __shared__ int   redI[4];
    const int tid = threadIdx.x;
    const int rowBase = blockIdx.x * 64;
    if (tid < 64) flg[tid] = flags[rowBase + tid];
    __syncthreads();
    const int lane = tid & 63, w = tid >> 6;
    for (int rr = 0; rr < 64; ++rr) {
        if (!flg[rr]) continue;
        const int row = rowBase + rr;
        float rv[8];
        *(float4*)&rv[0] = *(const float4*)(src + (size_t)row * D_ + lane * 8);
        *(float4*)&rv[4] = *(const float4*)(src + (size_t)row * D_ + lane * 8 + 4);
        float bm = INFINITY; int bi = 0;
        for (int c = w * 256; c < w * 256 + 256; ++c) {
            const float* cp = cb + (size_t)c * D_ + lane * 8;
            float4 c0 = *(const float4*)cp;
            float4 c1 = *(const float4*)(cp + 4);
            float dot = rv[0]*c0.x + rv[1]*c0.y + rv[2]*c0.z + rv[3]*c0.w
                      + rv[4]*c1.x + rv[5]*c1.y + rv[6]*c1.z + rv[7]*c1.w;
            #pragma unroll
            for (int m = 1; m < 64; m <<= 1) dot += __shfl_xor(dot, m);
            const float s = fmaf(-2.f, dot, norms_s[c]);
            if (s < bm) { bm = s; bi = c; }
        }
        if (lane == 0) { redM[w] = bm; redI[w] = bi; }
        __syncthreads();
        if (tid == 0) {
            float m1 = redM[0]; int i1 = redI[0];
            #pragma unroll
            for (int k = 1; k < 4; ++k)
                if (redM[k] < m1) { m1 = redM[k]; i1 = redI[k]; }
            idx_i[row] = i1;
            idx_f[(size_t)row * Q_ + q] = (float)i1;
        }
        __syncthreads();
    }
}

// -------------------------------------------------------------------------
// residual update: newres = res - cb[idx] (exact f32); loss; final qout
__global__ __launch_bounds__(256)
void update_kernel(const float* __restrict__ src, float* __restrict__ dst,
                   const float* __restrict__ x, const float* __restrict__ cb,
                   const int* __restrict__ idx_i, float* __restrict__ loss_out,
                   int is_last) {
    __shared__ int ids[64];
    const int tid = threadIdx.x;
    const int rowBase = blockIdx.x * 64;
    if (tid < 64) ids[tid] = idx_i[rowBase + tid];
    __syncthreads();
    float lsum = 0.f;
    #pragma unroll 4
    for (int e4 = tid; e4 < 64 * D_ / 4; e4 += 256) {
        const int row  = e4 >> 7;
        const int d    = (e4 & 127) * 4;
        const int code = ids[row];
        const size_t off = (size_t)(rowBase + row) * D_ + d;
        float4 r = *(const float4*)(src + off);
        float4 e = *(const float4*)(cb + (size_t)code * D_ + d);
        float4 nr = make_float4(r.x - e.x, r.y - e.y, r.z - e.z, r.w - e.w);
        lsum += nr.x * nr.x + nr.y * nr.y + nr.z * nr.z + nr.w * nr.w;
        if (is_last) {
            float4 xv = *(const float4*)(x + off);
            *(float4*)(dst + off) = make_float4(xv.x - nr.x, xv.y - nr.y,
                                                xv.z - nr.z, xv.w - nr.w);
        } else {
            *(float4*)(dst + off) = nr;
        }
    }
    #pragma unroll
    for (int m = 1; m < 64; m <<= 1) lsum += __shfl_xor(lsum, m);
    if ((tid & 63) == 0)
        atomicAdd(loss_out, lsum * (1.0f / ((float)ROWS * (float)D_)));
}

// -------------------------------------------------------------------------
extern "C" void kernel_launch(void* const* d_in, const int* in_sizes, int n_in,
                              void* d_out, int out_size, void* d_ws, size_t ws_size,
                              hipStream_t stream) {
    const float* x  = (const float*)d_in[0];   // [B,N,D]
    const float* cb = (const float*)d_in[1];   // [Q,C,D]

    float* qout   = (float*)d_out;                                  // doubles as residual
    float* idx_f  = (float*)d_out + (size_t)ROWS * D_;              // [ROWS][Q_] as floats
    float* losses = idx_f + (size_t)ROWS * Q_;                      // [Q_]

    char* w = (char*)d_ws;
    unsigned short* cb_hi = (unsigned short*)w;                     // Q*C*D bf16
    unsigned short* cb_lo = cb_hi + (size_t)Q_ * C_ * D_;
    float* norms = (float*)(cb_lo + (size_t)Q_ * C_ * D_);          // Q*C
    float* st_m1 = norms + Q_ * C_;                                 // 4*ROWS
    float* st_m2 = st_m1 + 4 * ROWS;
    int*   st_i1 = (int*)(st_m2 + 4 * ROWS);
    int*   idx_i = st_i1 + 4 * ROWS;
    int*   flags = idx_i + ROWS;

    hipMemsetAsync(losses, 0, Q_ * sizeof(float), stream);
    cb_convert_kernel<<<Q_ * C_ * D_ / 1024, 256, 0, stream>>>(cb, cb_hi, cb_lo);
    code_norms_kernel<<<Q_ * C_ / 4, 256, 0, stream>>>(cb, norms);

    for (int q = 0; q < Q_; ++q) {
        const float* src = (q == 0) ? x : qout;
        const float* cb_s = cb + (size_t)q * C_ * D_;
        rvq_gemm_kernel<<<dim3(ROWS / 128, 2), 256, 0, stream>>>(
            src, cb_hi + (size_t)q * C_ * D_, cb_lo + (size_t)q * C_ * D_,
            norms + (size_t)q * C_, st_m1, st_m2, st_i1);
        merge_kernel<<<ROWS / 256, 256, 0, stream>>>(
            st_m1, st_m2, st_i1, idx_i, flags, idx_f, q);
        rescue_kernel<<<ROWS / 64, 256, 0, stream>>>(
            src, cb_s, norms + (size_t)q * C_, idx_i, idx_f, flags, q);
        update_kernel<<<ROWS / 64, 256, 0, stream>>>(
            src, qout, x, cb_s, idx_i, losses + q, (q == Q_ - 1) ? 1 : 0);
    }
}

// Round 4
// 2048.995 us; speedup vs baseline: 2.1898x; 1.5880x over previous
//
#include <hip/hip_runtime.h>
#include <math.h>

// Problem constants (ResidualVQ: B=8, N=4096, D=512, C=1024, Q=8)
#define B_   8
#define N_   4096
#define D_   512
#define C_   1024
#define Q_   8
#define ROWS (B_ * N_)   // 32768 token rows

#define TAU  0.1f        // rescue margin; approx-score error bound ~5e-4
#define RCH  8           // rows per rescue chunk

typedef __attribute__((ext_vector_type(8))) short bf16x8;
typedef __attribute__((ext_vector_type(4))) float f32x4;

// round-to-nearest-even f32 -> bf16 (bits)
__device__ __forceinline__ unsigned short bf16rn(float f) {
    unsigned int u = __builtin_bit_cast(unsigned int, f);
    return (unsigned short)((u + 0x7fffu + ((u >> 16) & 1u)) >> 16);
}
__device__ __forceinline__ float bf16f(unsigned short h) {
    unsigned int u = ((unsigned int)h) << 16;
    return __builtin_bit_cast(float, u);
}
// LDS byte offset for tile [row][32 bf16], XOR-swizzled (<=2-way conflicts)
__device__ __forceinline__ int swzoff(int row, int q) {
    return row * 64 + ((q ^ ((row >> 1) & 3)) << 4);
}

// -------------------------------------------------------------------------
// codebook f32 -> hi/lo bf16 (once per call)
__global__ __launch_bounds__(256)
void cb_convert_kernel(const float* __restrict__ cb,
                       unsigned short* __restrict__ hi,
                       unsigned short* __restrict__ lo) {
    const int i4 = blockIdx.x * 256 + threadIdx.x;      // float4 index
    float4 v = ((const float4*)cb)[i4];
    ushort4 h, l;
    h.x = bf16rn(v.x); l.x = bf16rn(v.x - bf16f(h.x));
    h.y = bf16rn(v.y); l.y = bf16rn(v.y - bf16f(h.y));
    h.z = bf16rn(v.z); l.z = bf16rn(v.z - bf16f(h.z));
    h.w = bf16rn(v.w); l.w = bf16rn(v.w - bf16f(h.w));
    ((ushort4*)hi)[i4] = h;
    ((ushort4*)lo)[i4] = l;
}

// ||e||^2 for every code of every stage (exact f32)
__global__ __launch_bounds__(256)
void code_norms_kernel(const float* __restrict__ cb, float* __restrict__ norms) {
    const int code = blockIdx.x * 4 + (threadIdx.x >> 6);
    const int lane = threadIdx.x & 63;
    const float* p = cb + (size_t)code * D_;
    float s = 0.f;
    #pragma unroll
    for (int d = lane * 4; d < D_; d += 256) {
        float4 v = *(const float4*)(p + d);
        s += v.x * v.x + v.y * v.y + v.z * v.z + v.w * v.w;
    }
    #pragma unroll
    for (int m = 1; m < 64; m <<= 1) s += __shfl_xor(s, m);
    if (lane == 0) norms[code] = s;
}

// -------------------------------------------------------------------------
// Split-bf16 MFMA scoring GEMM with per-row top-2 tracking.
// grid = (ROWS/128, 2 halves of C). Block: 256 thr = 4 waves (2 row x 2 code).
__global__ __launch_bounds__(256, 2)
void rvq_gemm_kernel(const float* __restrict__ src,          // residual [ROWS][D_]
                     const unsigned short* __restrict__ cbh, // stage cb hi [C_][D_]
                     const unsigned short* __restrict__ cbl, // stage cb lo
                     const float* __restrict__ norms_s,      // [C_]
                     float* __restrict__ st_m1,              // [4][ROWS]
                     float* __restrict__ st_m2,              // [4][ROWS]
                     int* __restrict__ st_i1)                // [4][ROWS]
{
    __shared__ char lds[32768];
    char* AhiB = lds;
    char* AloB = lds + 8192;
    char* BhiB = lds + 16384;
    char* BloB = lds + 24576;

    const int tid  = threadIdx.x;
    const int lane = tid & 63;
    const int lc   = lane & 15;        // code lane / row lane within frag
    const int lq   = lane >> 4;        // k-chunk of fragment
    const int wv   = tid >> 6;
    const int wr   = wv >> 1;          // wave row-half (0..1)
    const int wc   = wv & 1;           // wave code-half (0..1)
    const int rowBase = blockIdx.x * 128;
    const int half = blockIdx.y;

    float c_m1 = INFINITY, c_m2 = INFINITY;
    int   c_i1 = 0;

    const int arow  = tid >> 1;        // 0..127
    const int ahalf = tid & 1;         // which 16-k half

    for (int chunk = 0; chunk < 4; ++chunk) {
        const int codeBase = half * 512 + chunk * 128;
        f32x4 acc[4][4];
        #pragma unroll
        for (int m = 0; m < 4; ++m)
            #pragma unroll
            for (int n = 0; n < 4; ++n) acc[m][n] = (f32x4){0.f, 0.f, 0.f, 0.f};

        for (int kt = 0; kt < D_ / 32; ++kt) {
            __syncthreads();   // previous compute finished before restaging
            // ---- stage A (residual f32 -> hi/lo bf16 in regs -> LDS)
            {
                const float* ap = src + (size_t)(rowBase + arow) * D_ + kt * 32 + ahalf * 16;
                float fv[16];
                *(float4*)&fv[0]  = ((const float4*)ap)[0];
                *(float4*)&fv[4]  = ((const float4*)ap)[1];
                *(float4*)&fv[8]  = ((const float4*)ap)[2];
                *(float4*)&fv[12] = ((const float4*)ap)[3];
                bf16x8 H0, H1, L0, L1;
                #pragma unroll
                for (int j = 0; j < 8; ++j) {
                    unsigned short h0 = bf16rn(fv[j]);
                    H0[j] = (short)h0;
                    L0[j] = (short)bf16rn(fv[j] - bf16f(h0));
                    unsigned short h1 = bf16rn(fv[j + 8]);
                    H1[j] = (short)h1;
                    L1[j] = (short)bf16rn(fv[j + 8] - bf16f(h1));
                }
                const int q0 = ahalf * 2;
                *(bf16x8*)(AhiB + swzoff(arow, q0))     = H0;
                *(bf16x8*)(AhiB + swzoff(arow, q0 + 1)) = H1;
                *(bf16x8*)(AloB + swzoff(arow, q0))     = L0;
                *(bf16x8*)(AloB + swzoff(arow, q0 + 1)) = L1;
            }
            // ---- stage B (pre-converted bf16 hi/lo)
            {
                const size_t boff = (size_t)(codeBase + arow) * D_ + kt * 32 + ahalf * 16;
                bf16x8 bh0 = *(const bf16x8*)(cbh + boff);
                bf16x8 bh1 = *(const bf16x8*)(cbh + boff + 8);
                bf16x8 bl0 = *(const bf16x8*)(cbl + boff);
                bf16x8 bl1 = *(const bf16x8*)(cbl + boff + 8);
                const int q0 = ahalf * 2;
                *(bf16x8*)(BhiB + swzoff(arow, q0))     = bh0;
                *(bf16x8*)(BhiB + swzoff(arow, q0 + 1)) = bh1;
                *(bf16x8*)(BloB + swzoff(arow, q0))     = bl0;
                *(bf16x8*)(BloB + swzoff(arow, q0 + 1)) = bl1;
            }
            __syncthreads();
            // ---- fragments + MFMA (3 split terms, shared accumulator)
            bf16x8 ah[4], al[4], bh[4], bl[4];
            #pragma unroll
            for (int m = 0; m < 4; ++m) {
                const int r = wr * 64 + m * 16 + lc;
                ah[m] = *(const bf16x8*)(AhiB + swzoff(r, lq));
                al[m] = *(const bf16x8*)(AloB + swzoff(r, lq));
            }
            #pragma unroll
            for (int n = 0; n < 4; ++n) {
                const int c = wc * 64 + n * 16 + lc;
                bh[n] = *(const bf16x8*)(BhiB + swzoff(c, lq));
                bl[n] = *(const bf16x8*)(BloB + swzoff(c, lq));
            }
            #pragma unroll
            for (int m = 0; m < 4; ++m)
                #pragma unroll
                for (int n = 0; n < 4; ++n) {
                    acc[m][n] = __builtin_amdgcn_mfma_f32_16x16x32_bf16(ah[m], bh[n], acc[m][n], 0, 0, 0);
                    acc[m][n] = __builtin_amdgcn_mfma_f32_16x16x32_bf16(ah[m], bl[n], acc[m][n], 0, 0, 0);
                    acc[m][n] = __builtin_amdgcn_mfma_f32_16x16x32_bf16(al[m], bh[n], acc[m][n], 0, 0, 0);
                }
        }

        // ---- fold chunk scores into carried top-2
        const int cbase = codeBase + wc * 64;
        const float nrm0 = norms_s[cbase + lc];
        const float nrm1 = norms_s[cbase + 16 + lc];
        const float nrm2 = norms_s[cbase + 32 + lc];
        const float nrm3 = norms_s[cbase + 48 + lc];
        #pragma unroll
        for (int m = 0; m < 4; ++m) {
            #pragma unroll
            for (int r = 0; r < 4; ++r) {
                float s0 = fmaf(-2.f, acc[m][0][r], nrm0);
                float s1 = fmaf(-2.f, acc[m][1][r], nrm1);
                float s2 = fmaf(-2.f, acc[m][2][r], nrm2);
                float s3 = fmaf(-2.f, acc[m][3][r], nrm3);
                float m1 = s0, m2 = INFINITY;
                int   i1 = cbase + lc;
                if (s1 < m1) { m2 = m1; m1 = s1; i1 = cbase + 16 + lc; } else m2 = fminf(m2, s1);
                if (s2 < m1) { m2 = m1; m1 = s2; i1 = cbase + 32 + lc; } else m2 = fminf(m2, s2);
                if (s3 < m1) { m2 = m1; m1 = s3; i1 = cbase + 48 + lc; } else m2 = fminf(m2, s3);
                #pragma unroll
                for (int d = 1; d < 16; d <<= 1) {
                    float om1 = __shfl_xor(m1, d);
                    int   oi1 = __shfl_xor(i1, d);
                    float om2 = __shfl_xor(m2, d);
                    bool take = (om1 < m1) || (om1 == m1 && oi1 < i1);
                    float lose1 = take ? m1 : om1;
                    m2 = fminf(fminf(m2, om2), lose1);
                    m1 = take ? om1 : m1;
                    i1 = take ? oi1 : i1;
                }
                if (lc == (m * 4 + r)) {
                    bool take = (m1 < c_m1) || (m1 == c_m1 && i1 < c_i1);
                    float lose1 = take ? c_m1 : m1;
                    c_m2 = fminf(fminf(c_m2, m2), lose1);
                    c_m1 = take ? m1 : c_m1;
                    c_i1 = take ? i1 : c_i1;
                }
            }
        }
    }

    const int myrow = rowBase + wr * 64 + (lc >> 2) * 16 + lq * 4 + (lc & 3);
    const int quarter = half * 2 + wc;
    st_m1[quarter * ROWS + myrow] = c_m1;
    st_m2[quarter * ROWS + myrow] = c_m2;
    st_i1[quarter * ROWS + myrow] = c_i1;
}

// -------------------------------------------------------------------------
// merge 4 quarters -> final idx; near-tie rows appended to compact rescue list
__global__ __launch_bounds__(256)
void merge_kernel(const float* __restrict__ st_m1, const float* __restrict__ st_m2,
                  const int* __restrict__ st_i1,
                  int* __restrict__ idx_i, float* __restrict__ idx_f,
                  int* __restrict__ list, int* __restrict__ nflag, int q) {
    const int row = blockIdx.x * 256 + threadIdx.x;
    float m1 = st_m1[row], m2 = st_m2[row];
    int   i1 = st_i1[row];
    #pragma unroll
    for (int qt = 1; qt < 4; ++qt) {
        float om1 = st_m1[qt * ROWS + row];
        float om2 = st_m2[qt * ROWS + row];
        int   oi1 = st_i1[qt * ROWS + row];
        if (om1 < m1) { m2 = fminf(m1, om2); m1 = om1; i1 = oi1; }
        else          { m2 = fminf(m2, om1); }
    }
    idx_i[row] = i1;
    idx_f[(size_t)row * Q_ + q] = (float)i1;
    if (m2 - m1 < TAU) {
        const int p = atomicAdd(nflag, 1);
        list[p] = row;
    }
}

// -------------------------------------------------------------------------
// Exact-f32 re-argmin for near-tie rows, compact-list driven.
// Fixed grid (256 blocks), grid-stride over chunks of RCH gathered rows.
// Each thread owns 4 codes (all 1024 in one pass) x all RCH rows.
__global__ __launch_bounds__(256)
void rescue_kernel(const float* __restrict__ src, const float* __restrict__ cb,
                   const float* __restrict__ norms_s,
                   const int* __restrict__ list, const int* __restrict__ nflag_p,
                   int* __restrict__ idx_i, float* __restrict__ idx_f, int q)
{
    __shared__ float As[D_][RCH];      // residual rows, [k][row] (16 KB)
    __shared__ int   rows_s[RCH];
    __shared__ float wm[4][RCH];
    __shared__ int   wi[4][RCH];
    const int nflag = nflag_p[0];
    const int tid = threadIdx.x;

    for (int chunk = blockIdx.x; chunk * RCH < nflag; chunk += gridDim.x) {
        __syncthreads();   // previous chunk's readers done before overwrite
        if (tid < RCH) {
            const int li = chunk * RCH + tid;
            rows_s[tid] = list[li < nflag ? li : nflag - 1];   // pad = dup last
        }
        __syncthreads();
        // stage 8 rows x 512 f32, transposed [k][row]
        #pragma unroll
        for (int i = 0; i < 4; ++i) {
            const int v  = tid + 256 * i;       // float4 unit 0..1023
            const int r  = v >> 7;
            const int k4 = (v & 127) * 4;
            float4 f = *(const float4*)(src + (size_t)rows_s[r] * D_ + k4);
            As[k4 + 0][r] = f.x; As[k4 + 1][r] = f.y;
            As[k4 + 2][r] = f.z; As[k4 + 3][r] = f.w;
        }
        __syncthreads();

        float acc[4][RCH];
        #pragma unroll
        for (int j = 0; j < 4; ++j)
            #pragma unroll
            for (int r = 0; r < RCH; ++r) acc[j][r] = 0.f;

        for (int k = 0; k < D_; k += 4) {
            float4 bq[4];
            #pragma unroll
            for (int j = 0; j < 4; ++j)
                bq[j] = *(const float4*)(cb + (size_t)(tid + 256 * j) * D_ + k);
            const float* bp = (const float*)&bq[0];
            const float* ap = &As[k][0];        // 32 consecutive floats, uniform addr
            #pragma unroll
            for (int e = 0; e < 4; ++e)
                #pragma unroll
                for (int r = 0; r < RCH; ++r) {
                    const float a = ap[e * RCH + r];
                    #pragma unroll
                    for (int j = 0; j < 4; ++j)
                        acc[j][r] = fmaf(bp[j * 4 + e], a, acc[j][r]);
                }
        }

        // per-thread scores -> per-row running min (codes ascending in j)
        float m1[RCH]; int i1[RCH];
        #pragma unroll
        for (int r = 0; r < RCH; ++r) { m1[r] = INFINITY; i1[r] = 0; }
        #pragma unroll
        for (int j = 0; j < 4; ++j) {
            const int c = tid + 256 * j;
            const float nr = norms_s[c];
            #pragma unroll
            for (int r = 0; r < RCH; ++r) {
                const float s = fmaf(-2.f, acc[j][r], nr);
                if (s < m1[r]) { m1[r] = s; i1[r] = c; }
            }
        }
        // wave butterfly (64 lanes), index tie-break
        #pragma unroll
        for (int d = 1; d < 64; d <<= 1)
            #pragma unroll
            for (int r = 0; r < RCH; ++r) {
                const float om = __shfl_xor(m1[r], d);
                const int   oi = __shfl_xor(i1[r], d);
                if (om < m1[r] || (om == m1[r] && oi < i1[r])) { m1[r] = om; i1[r] = oi; }
            }
        if ((tid & 63) == 0)
            #pragma unroll
            for (int r = 0; r < RCH; ++r) { wm[tid >> 6][r] = m1[r]; wi[tid >> 6][r] = i1[r]; }
        __syncthreads();
        if (tid < RCH) {
            float bm = wm[0][tid]; int bi = wi[0][tid];
            #pragma unroll
            for (int w = 1; w < 4; ++w)
                if (wm[w][tid] < bm || (wm[w][tid] == bm && wi[w][tid] < bi)) {
                    bm = wm[w][tid]; bi = wi[w][tid];
                }
            const int li = chunk * RCH + tid;
            if (li < nflag) {                  // skip padding duplicates
                const int row = rows_s[tid];
                idx_i[row] = bi;
                idx_f[(size_t)row * Q_ + q] = (float)bi;
            }
        }
    }
}

// -------------------------------------------------------------------------
// residual update: newres = res - cb[idx] (exact f32); loss; final qout
__global__ __launch_bounds__(256)
void update_kernel(const float* __restrict__ src, float* __restrict__ dst,
                   const float* __restrict__ x, const float* __restrict__ cb,
                   const int* __restrict__ idx_i, float* __restrict__ loss_out,
                   int is_last) {
    __shared__ int ids[64];
    const int tid = threadIdx.x;
    const int rowBase = blockIdx.x * 64;
    if (tid < 64) ids[tid] = idx_i[rowBase + tid];
    __syncthreads();
    float lsum = 0.f;
    #pragma unroll 4
    for (int e4 = tid; e4 < 64 * D_ / 4; e4 += 256) {
        const int row  = e4 >> 7;
        const int d    = (e4 & 127) * 4;
        const int code = ids[row];
        const size_t off = (size_t)(rowBase + row) * D_ + d;
        float4 r = *(const float4*)(src + off);
        float4 e = *(const float4*)(cb + (size_t)code * D_ + d);
        float4 nr = make_float4(r.x - e.x, r.y - e.y, r.z - e.z, r.w - e.w);
        lsum += nr.x * nr.x + nr.y * nr.y + nr.z * nr.z + nr.w * nr.w;
        if (is_last) {
            float4 xv = *(const float4*)(x + off);
            *(float4*)(dst + off) = make_float4(xv.x - nr.x, xv.y - nr.y,
                                                xv.z - nr.z, xv.w - nr.w);
        } else {
            *(float4*)(dst + off) = nr;
        }
    }
    #pragma unroll
    for (int m = 1; m < 64; m <<= 1) lsum += __shfl_xor(lsum, m);
    if ((tid & 63) == 0)
        atomicAdd(loss_out, lsum * (1.0f / ((float)ROWS * (float)D_)));
}

// -------------------------------------------------------------------------
extern "C" void kernel_launch(void* const* d_in, const int* in_sizes, int n_in,
                              void* d_out, int out_size, void* d_ws, size_t ws_size,
                              hipStream_t stream) {
    const float* x  = (const float*)d_in[0];   // [B,N,D]
    const float* cb = (const float*)d_in[1];   // [Q,C,D]

    float* qout   = (float*)d_out;                                  // doubles as residual
    float* idx_f  = (float*)d_out + (size_t)ROWS * D_;              // [ROWS][Q_] as floats
    float* losses = idx_f + (size_t)ROWS * Q_;                      // [Q_]

    char* w = (char*)d_ws;
    unsigned short* cb_hi = (unsigned short*)w;                     // Q*C*D bf16
    unsigned short* cb_lo = cb_hi + (size_t)Q_ * C_ * D_;
    float* norms = (float*)(cb_lo + (size_t)Q_ * C_ * D_);          // Q*C
    float* st_m1 = norms + Q_ * C_;                                 // 4*ROWS
    float* st_m2 = st_m1 + 4 * ROWS;
    int*   st_i1 = (int*)(st_m2 + 4 * ROWS);
    int*   idx_i = st_i1 + 4 * ROWS;                                // ROWS
    int*   list  = idx_i + ROWS;                                    // ROWS
    int*   nflag = list + ROWS;                                     // 1

    hipMemsetAsync(losses, 0, Q_ * sizeof(float), stream);
    cb_convert_kernel<<<Q_ * C_ * D_ / 1024, 256, 0, stream>>>(cb, cb_hi, cb_lo);
    code_norms_kernel<<<Q_ * C_ / 4, 256, 0, stream>>>(cb, norms);

    for (int q = 0; q < Q_; ++q) {
        const float* src = (q == 0) ? x : qout;
        const float* cb_s = cb + (size_t)q * C_ * D_;
        rvq_gemm_kernel<<<dim3(ROWS / 128, 2), 256, 0, stream>>>(
            src, cb_hi + (size_t)q * C_ * D_, cb_lo + (size_t)q * C_ * D_,
            norms + (size_t)q * C_, st_m1, st_m2, st_i1);
        hipMemsetAsync(nflag, 0, sizeof(int), stream);
        merge_kernel<<<ROWS / 256, 256, 0, stream>>>(
            st_m1, st_m2, st_i1, idx_i, idx_f, list, nflag, q);
        rescue_kernel<<<256, 256, 0, stream>>>(
            src, cb_s, norms + (size_t)q * C_, list, nflag, idx_i, idx_f, q);
        update_kernel<<<ROWS / 64, 256, 0, stream>>>(
            src, qout, x, cb_s, idx_i, losses + q, (q == Q_ - 1) ? 1 : 0);
    }
}